// Round 2
// 334.855 us; speedup vs baseline: 1.1120x; 1.1120x over previous
//
#include <hip/hip_runtime.h>
#include <cstdint>

#define NSTEP 1000
#define NELEM 45056          // 16 * 2816  (n*s = 16 slices of 64x44)
#define HW    2816           // 64 * 44
#define EPB   64             // elements per block == consumer wave width
#define PW    4              // producer waves per block
#define BLK   ((PW + 1) * 64)// 320 threads: 4 producer waves + 1 consumer wave
#define WIN   40             // k-steps per LDS window; NSTEP % WIN == 0
#define NWIN  (NSTEP / WIN)  // 25

// ---------- compile-time fp64 DDIM schedule (bit-exact vs np.linspace+cumprod) ----------
struct AlphTab { float a[NSTEP + 1]; };

constexpr AlphTab make_alph() {
    AlphTab t{};
    t.a[0] = 1.0f;
    double alph = 1.0;
    const double start = 1e-4, stop = 0.02;
    const double step = (stop - start) / 999.0;
    for (int i = 0; i < NSTEP; ++i) {
        double beta = (i == NSTEP - 1) ? stop : ((double)i * step + start);
        alph *= (1.0 - beta);
        t.a[i + 1] = (float)alph;
    }
    return t;
}
constexpr AlphTab ALPH = make_alph();

// ---------- Threefry-2x32-20 (partitionable-mode usage: ctr=(0,j), out = x0^x1) ----------
__device__ __forceinline__ void tf20(uint32_t K0, uint32_t K1, uint32_t K2,
                                     uint32_t& x0, uint32_t& x1) {
    x0 += K0; x1 += K1;
#define TFR(r) { x0 += x1; x1 = ((x1 << r) | (x1 >> (32 - r))); x1 ^= x0; }
    TFR(13) TFR(15) TFR(26) TFR(6)
    x0 += K1; x1 += K2 + 1u;
    TFR(17) TFR(29) TFR(16) TFR(24)
    x0 += K2; x1 += K0 + 2u;
    TFR(13) TFR(15) TFR(26) TFR(6)
    x0 += K0; x1 += K1 + 3u;
    TFR(17) TFR(29) TFR(16) TFR(24)
    x0 += K1; x1 += K2 + 4u;
    TFR(13) TFR(15) TFR(26) TFR(6)
    x0 += K2; x1 += K0 + 5u;
#undef TFR
}

// bits -> erfinv(u)*u-ish; returns p*u == erfinv(u); caller scales by sqrt2*c1
__device__ __forceinline__ float bits_to_erfinv(uint32_t bits) {
    const float f2 = __uint_as_float((bits >> 9) | 0x3F800000u) - 1.0f;
    const float u  = f2 * 2.0f - 0.99999994f;
    const float t1 = (1.0f - u) * (1.0f + u);
    const float w  = __log2f(t1) * -0.6931472f;
    const bool  lt = w < 5.0f;
    const float sw = __builtin_amdgcn_sqrtf(w);      // far branch only; 1-ulp ok
    const float ww = lt ? (w - 2.5f) : (sw - 3.0f);
    float p =          lt ?  2.81022636e-08f : -0.000200214257f;
    p = fmaf(p, ww,    lt ?  3.43273939e-07f :  0.000100950558f);
    p = fmaf(p, ww,    lt ? -3.5233877e-06f  :  0.00134934322f);
    p = fmaf(p, ww,    lt ? -4.39150654e-06f : -0.00367342844f);
    p = fmaf(p, ww,    lt ?  0.00021858087f  :  0.00573950773f);
    p = fmaf(p, ww,    lt ? -0.00125372503f  : -0.0076224613f);
    p = fmaf(p, ww,    lt ? -0.00417768164f  :  0.00943887047f);
    p = fmaf(p, ww,    lt ?  0.246640727f    :  1.00167406f);
    p = fmaf(p, ww,    lt ?  1.50140941f     :  2.83297682f);
    return p * u;
}

// =====================================================================
// Fused producer-consumer kernel.
//   grid = NELEM/EPB = 704 blocks x 320 threads (5 waves).
//   waves 0..3 (producers): threefry+erfinv noise d_k for a WIN-step
//     window into LDS double-buffer (round-robin k%PW per wave).
//   wave 4 (consumer): serial DDIM scan over 64 elements, reading d_k
//     from LDS, writing sil_0 predictions straight to out.
//   Schedule constants in an LDS table (one-time init, ~3 rows/thread).
// LDS: tab 32 KB + dbuf 20 KB = 52.5 KB -> 3 blocks/CU (need 2.75).
// =====================================================================
__global__ __launch_bounds__(BLK)
void fused_kernel(const float* __restrict__ skes,
                  const float* __restrict__ silT,
                  const float* __restrict__ wskes,
                  const float* __restrict__ wsil_p,
                  const float* __restrict__ tsc_p,
                  float* __restrict__ out) {
    // tab[k]: {c1s, e, k0, k1, A, tb2, k2, pad}
    __shared__ __align__(16) uint32_t tab[NSTEP][8];
    __shared__ __align__(16) float dbuf[2][WIN][EPB];

    const float wsil = wsil_p[0];
    const float tsc  = tsc_p[0];
    const float L2E2 = 2.8853900817779268f;      // 2*log2(e)

    // ---- one-time schedule init: ~3.2 rows/thread ----
    for (int k = (int)threadIdx.x; k < NSTEP; k += BLK) {
        const int t = 999 - k;
        const float at  = ALPH.a[t + 1];
        const float atn = ALPH.a[t];
        const float c1 = 0.1f * sqrtf((1.0f - at / atn) * (1.0f - atn) / (1.0f - at));
        const float c2 = sqrtf(fmaxf(1.0f - atn - c1 * c1, 0.0f));
        const float rs = 1.0f / sqrtf(1.0f - at);
        const float A  = sqrtf(atn) - c2 * sqrtf(at) * rs;
        const float e  = c2 * rs;
        const float temb = tsc * ((float)t / 1000.0f);
        // fold_in(key(42), t): key <- threefry(key=[0,42], ctr=[0,t])
        uint32_t k0 = 0u, k1 = (uint32_t)t;
        tf20(0u, 42u, 0x1BD11BDAu ^ 42u, k0, k1);
        tab[k][0] = __float_as_uint(c1 * 1.4142135f);
        tab[k][1] = __float_as_uint(e);
        tab[k][2] = k0;
        tab[k][3] = k1;
        tab[k][4] = __float_as_uint(A);
        tab[k][5] = __float_as_uint(temb * L2E2);
        tab[k][6] = k0 ^ k1 ^ 0x1BD11BDAu;
        tab[k][7] = 0u;
    }

    const int wid  = (int)(threadIdx.x >> 6);
    const int lane = (int)(threadIdx.x & 63);
    const int j    = (int)(blockIdx.x * EPB) + lane;

    const float sT = silT[j];

    // consumer-only per-lane state (wave-uniform guard)
    float cc2 = 0.0f, ws2 = 0.0f, sil = 0.0f;
    if (wid == PW) {
        const int ns = j / HW;
        const int hw = j - ns * HW;
        const int n  = ns >> 3;
        const int ss = ns & 7;
        const float* sk = skes + (size_t)((n * 3) * 8 + ss) * HW + hw;
        const float w0 = wskes[0], w1 = wskes[1], w2 = wskes[2];
        const float cond = fmaf(w2, sk[2 * 8 * HW], fmaf(w1, sk[8 * HW], w0 * sk[0]));
        cc2 = cond * L2E2;
        ws2 = wsil * L2E2;
        sil = sT;
    }

    __syncthreads();   // tab ready

    // ---- prologue: producers fill window 0 into dbuf[0] ----
    if (wid < PW) {
        float* db = &dbuf[0][0][0];
#pragma unroll 2
        for (int kk = wid; kk < WIN; kk += PW) {
            const uint4 ta    = *(const uint4*)&tab[kk][0];   // c1s, e, k0, k1
            const uint32_t k2 = tab[kk][6];
            uint32_t x0 = 0u, x1 = (uint32_t)j;               // partitionable ctr (0, j)
            tf20(ta.z, ta.w, k2, x0, x1);
            const float ei = bits_to_erfinv(x0 ^ x1);
            db[kk * EPB + lane] =
                fmaf(__uint_as_float(ta.x), ei, __uint_as_float(ta.y) * sT);
        }
    }
    __syncthreads();   // window 0 ready

    float* op = out + j;

    for (int w = 0; w < NWIN; ++w) {
        if (wid < PW) {
            // ---- producers: fill window w+1 into the other buffer ----
            if (w + 1 < NWIN) {
                float* db = &dbuf[(w + 1) & 1][0][0];
                const int kbase = (w + 1) * WIN;
#pragma unroll 2
                for (int kk = wid; kk < WIN; kk += PW) {
                    const int k = kbase + kk;
                    const uint4 ta    = *(const uint4*)&tab[k][0];
                    const uint32_t k2 = tab[k][6];
                    uint32_t x0 = 0u, x1 = (uint32_t)j;
                    tf20(ta.z, ta.w, k2, x0, x1);
                    const float ei = bits_to_erfinv(x0 ^ x1);
                    db[kk * EPB + lane] =
                        fmaf(__uint_as_float(ta.x), ei, __uint_as_float(ta.y) * sT);
                }
            }
        } else {
            // ---- consumer: serial scan over window w ----
            const float* db = &dbuf[w & 1][0][0];
            const int kbase = w * WIN;
#pragma unroll 4
            for (int kk = 0; kk < WIN; ++kk) {
                const uint2 tt = *(const uint2*)&tab[kbase + kk][4];  // A, tb2
                const float A  = __uint_as_float(tt.x);
                const float tb = __uint_as_float(tt.y);
                const float e2 = __builtin_amdgcn_exp2f(fmaf(ws2, sil, cc2 + tb));
                const float r  = __builtin_amdgcn_rcpf(e2 + 1.0f);
                const float s0 = fmaf(-2.0f, r, 1.0f);
                *op = s0; op += NELEM;
                sil = fmaf(A, s0, db[kk * EPB + lane]);
            }
        }
        __syncthreads();   // window w consumed / window w+1 ready
    }
}

extern "C" void kernel_launch(void* const* d_in, const int* in_sizes, int n_in,
                              void* d_out, int out_size, void* d_ws, size_t ws_size,
                              hipStream_t stream) {
    const float* skes = (const float*)d_in[0];
    const float* silT = (const float*)d_in[1];
    const float* wsk  = (const float*)d_in[2];
    const float* wsil = (const float*)d_in[3];
    const float* tsc  = (const float*)d_in[4];
    float* out = (float*)d_out;
    (void)in_sizes; (void)n_in; (void)out_size; (void)d_ws; (void)ws_size;

    dim3 grid(NELEM / EPB), block(BLK);
    hipLaunchKernelGGL(fused_kernel, grid, block, 0, stream,
                       skes, silT, wsk, wsil, tsc, out);
}

// Round 3
// 321.369 us; speedup vs baseline: 1.1586x; 1.0420x over previous
//
#include <hip/hip_runtime.h>
#include <cstdint>

#define NSTEP 1000
#define NELEM 45056          // 16 * 2816  (n*s = 16 slices of 64x44)
#define HW    2816           // 64 * 44
#define EPB   64             // elements per block == consumer wave width
#define PW    8              // producer waves per block
#define BLK   ((PW + 1) * 64)// 576 threads: 8 producer waves + 1 consumer wave
#define WIN   40             // k-steps per LDS window; NSTEP % WIN == 0, WIN % PW == 0
#define SPP   (WIN / PW)     // 5 k-steps per producer wave per window
#define NWIN  (NSTEP / WIN)  // 25

// ---------- compile-time fp64 DDIM schedule (bit-exact vs np.linspace+cumprod) ----------
struct AlphTab { float a[NSTEP + 1]; };

constexpr AlphTab make_alph() {
    AlphTab t{};
    t.a[0] = 1.0f;
    double alph = 1.0;
    const double start = 1e-4, stop = 0.02;
    const double step = (stop - start) / 999.0;
    for (int i = 0; i < NSTEP; ++i) {
        double beta = (i == NSTEP - 1) ? stop : ((double)i * step + start);
        alph *= (1.0 - beta);
        t.a[i + 1] = (float)alph;
    }
    return t;
}
constexpr AlphTab ALPH = make_alph();

// ---------- Threefry-2x32-20 (partitionable-mode usage: ctr=(0,j), out = x0^x1) ----------
__device__ __forceinline__ void tf20(uint32_t K0, uint32_t K1, uint32_t K2,
                                     uint32_t& x0, uint32_t& x1) {
    x0 += K0; x1 += K1;
#define TFR(r) { x0 += x1; x1 = ((x1 << r) | (x1 >> (32 - r))); x1 ^= x0; }
    TFR(13) TFR(15) TFR(26) TFR(6)
    x0 += K1; x1 += K2 + 1u;
    TFR(17) TFR(29) TFR(16) TFR(24)
    x0 += K2; x1 += K0 + 2u;
    TFR(13) TFR(15) TFR(26) TFR(6)
    x0 += K0; x1 += K1 + 3u;
    TFR(17) TFR(29) TFR(16) TFR(24)
    x0 += K1; x1 += K2 + 4u;
    TFR(13) TFR(15) TFR(26) TFR(6)
    x0 += K2; x1 += K0 + 5u;
#undef TFR
}

// bits -> erfinv(u). Dual-poly, single select; wave-uniform skip of the far
// branch (P(any of 64 lanes far) ~ 19%). Bit-identical to the reference poly.
__device__ __forceinline__ float bits_to_erfinv(uint32_t bits) {
    const float f2 = __uint_as_float((bits >> 9) | 0x3F800000u) - 1.0f;
    const float u  = f2 * 2.0f - 0.99999994f;
    const float t1 = (1.0f - u) * (1.0f + u);
    const float w  = __log2f(t1) * -0.6931472f;
    const bool  lt = w < 5.0f;

    const float wwn = w - 2.5f;
    float pn =           2.81022636e-08f;
    pn = fmaf(pn, wwn,   3.43273939e-07f);
    pn = fmaf(pn, wwn,  -3.5233877e-06f);
    pn = fmaf(pn, wwn,  -4.39150654e-06f);
    pn = fmaf(pn, wwn,   0.00021858087f);
    pn = fmaf(pn, wwn,  -0.00125372503f);
    pn = fmaf(pn, wwn,  -0.00417768164f);
    pn = fmaf(pn, wwn,   0.246640727f);
    pn = fmaf(pn, wwn,   1.50140941f);

    float p = pn;
    if (__any(!lt)) {                                 // wave-uniform branch
        const float sw  = __builtin_amdgcn_sqrtf(w);  // w >= 0 always
        const float wwf = sw - 3.0f;
        float pf =           -0.000200214257f;
        pf = fmaf(pf, wwf,    0.000100950558f);
        pf = fmaf(pf, wwf,    0.00134934322f);
        pf = fmaf(pf, wwf,   -0.00367342844f);
        pf = fmaf(pf, wwf,    0.00573950773f);
        pf = fmaf(pf, wwf,   -0.0076224613f);
        pf = fmaf(pf, wwf,    0.00943887047f);
        pf = fmaf(pf, wwf,    1.00167406f);
        pf = fmaf(pf, wwf,    2.83297682f);
        p = lt ? pn : pf;
    }
    return p * u;
}

// =====================================================================
// Fused producer-consumer kernel.
//   grid = NELEM/EPB = 704 blocks x 576 threads (9 waves).
//   waves 0..7 (producers): threefry+erfinv noise d_k for a WIN-step
//     window into LDS double-buffer (5 k-steps per wave per window).
//   wave 8 (consumer): serial DDIM scan over 64 elements, reading d_k
//     from LDS, writing sil_0 predictions straight to out.
// LDS: tabP 16K + tabK2 4K + tabC 8K + dbuf 20K = 48 KB -> 3 blocks/CU,
// 27 waves/CU (~6.75/SIMD) for barrier-skew absorption.
// =====================================================================
__global__ __launch_bounds__(BLK)
void fused_kernel(const float* __restrict__ skes,
                  const float* __restrict__ silT,
                  const float* __restrict__ wskes,
                  const float* __restrict__ wsil_p,
                  const float* __restrict__ tsc_p,
                  float* __restrict__ out) {
    __shared__ __align__(16) uint4    tabP[NSTEP];   // {c1s, e, k0, k1}
    __shared__            uint32_t    tabK2[NSTEP];  // k2
    __shared__ __align__(8)  uint2    tabC[NSTEP];   // {A, temb*2log2e}
    __shared__ __align__(16) float    dbuf[2][WIN][EPB];

    const float wsil = wsil_p[0];
    const float tsc  = tsc_p[0];
    const float L2E2 = 2.8853900817779268f;      // 2*log2(e)

    // ---- one-time schedule init: 2 rows/thread ----
    for (int k = (int)threadIdx.x; k < NSTEP; k += BLK) {
        const int t = 999 - k;
        const float at  = ALPH.a[t + 1];
        const float atn = ALPH.a[t];
        const float c1 = 0.1f * sqrtf((1.0f - at / atn) * (1.0f - atn) / (1.0f - at));
        const float c2 = sqrtf(fmaxf(1.0f - atn - c1 * c1, 0.0f));
        const float rs = 1.0f / sqrtf(1.0f - at);
        const float A  = sqrtf(atn) - c2 * sqrtf(at) * rs;
        const float e  = c2 * rs;
        const float temb = tsc * ((float)t / 1000.0f);
        // fold_in(key(42), t): key <- threefry(key=[0,42], ctr=[0,t])
        uint32_t k0 = 0u, k1 = (uint32_t)t;
        tf20(0u, 42u, 0x1BD11BDAu ^ 42u, k0, k1);
        tabP[k]  = make_uint4(__float_as_uint(c1 * 1.4142135f),
                              __float_as_uint(e), k0, k1);
        tabK2[k] = k0 ^ k1 ^ 0x1BD11BDAu;
        tabC[k]  = make_uint2(__float_as_uint(A), __float_as_uint(temb * L2E2));
    }

    const int wid  = (int)(threadIdx.x >> 6);
    const int lane = (int)(threadIdx.x & 63);
    const int j    = (int)(blockIdx.x * EPB) + lane;

    const float sT = silT[j];

    // consumer-only per-lane state
    float cc2 = 0.0f, ws2 = 0.0f, sil = 0.0f;
    if (wid == PW) {
        const int ns = j / HW;
        const int hw = j - ns * HW;
        const int n  = ns >> 3;
        const int ss = ns & 7;
        const float* sk = skes + (size_t)((n * 3) * 8 + ss) * HW + hw;
        const float w0 = wskes[0], w1 = wskes[1], w2 = wskes[2];
        const float cond = fmaf(w2, sk[2 * 8 * HW], fmaf(w1, sk[8 * HW], w0 * sk[0]));
        cc2 = cond * L2E2;
        ws2 = wsil * L2E2;
        sil = sT;
    }

    __syncthreads();   // tab ready

    // ---- prologue: producers fill window 0 into dbuf[0] ----
    if (wid < PW) {
        float* db = &dbuf[0][0][0];
#pragma unroll
        for (int s = 0; s < SPP; ++s) {
            const int kk = wid + s * PW;
            const uint4 ta    = tabP[kk];
            const uint32_t k2 = tabK2[kk];
            uint32_t x0 = 0u, x1 = (uint32_t)j;   // partitionable ctr (0, j)
            tf20(ta.z, ta.w, k2, x0, x1);
            const float ei = bits_to_erfinv(x0 ^ x1);
            db[kk * EPB + lane] =
                fmaf(__uint_as_float(ta.x), ei, __uint_as_float(ta.y) * sT);
        }
    }
    __syncthreads();   // window 0 ready

    float* op = out + j;

    for (int w = 0; w < NWIN; ++w) {
        if (wid < PW) {
            // ---- producers: fill window w+1 into the other buffer ----
            if (w + 1 < NWIN) {
                float* db = &dbuf[(w + 1) & 1][0][0];
                const int kbase = (w + 1) * WIN;
#pragma unroll
                for (int s = 0; s < SPP; ++s) {
                    const int kk = wid + s * PW;
                    const int k  = kbase + kk;
                    const uint4 ta    = tabP[k];
                    const uint32_t k2 = tabK2[k];
                    uint32_t x0 = 0u, x1 = (uint32_t)j;
                    tf20(ta.z, ta.w, k2, x0, x1);
                    const float ei = bits_to_erfinv(x0 ^ x1);
                    db[kk * EPB + lane] =
                        fmaf(__uint_as_float(ta.x), ei, __uint_as_float(ta.y) * sT);
                }
            }
        } else {
            // ---- consumer: serial scan over window w ----
            const float* db = &dbuf[w & 1][0][0];
            const int kbase = w * WIN;
#pragma unroll 4
            for (int kk = 0; kk < WIN; ++kk) {
                const uint2 tt = tabC[kbase + kk];
                const float A  = __uint_as_float(tt.x);
                const float tb = __uint_as_float(tt.y);
                const float e2 = __builtin_amdgcn_exp2f(fmaf(ws2, sil, cc2 + tb));
                const float r  = __builtin_amdgcn_rcpf(e2 + 1.0f);
                const float s0 = fmaf(-2.0f, r, 1.0f);
                *op = s0; op += NELEM;
                sil = fmaf(A, s0, db[kk * EPB + lane]);
            }
        }
        __syncthreads();   // window w consumed / window w+1 ready
    }
}

extern "C" void kernel_launch(void* const* d_in, const int* in_sizes, int n_in,
                              void* d_out, int out_size, void* d_ws, size_t ws_size,
                              hipStream_t stream) {
    const float* skes = (const float*)d_in[0];
    const float* silT = (const float*)d_in[1];
    const float* wsk  = (const float*)d_in[2];
    const float* wsil = (const float*)d_in[3];
    const float* tsc  = (const float*)d_in[4];
    float* out = (float*)d_out;
    (void)in_sizes; (void)n_in; (void)out_size; (void)d_ws; (void)ws_size;

    dim3 grid(NELEM / EPB), block(BLK);
    hipLaunchKernelGGL(fused_kernel, grid, block, 0, stream,
                       skes, silT, wsk, wsil, tsc, out);
}